// Round 5
// baseline (204.886 us; speedup 1.0000x reference)
//
#include <hip/hip_runtime.h>
#include <hip/hip_bf16.h>

typedef unsigned short u16;
typedef unsigned int u32;
using short8 = __attribute__((ext_vector_type(8))) short;
using f32x4  = __attribute__((ext_vector_type(4))) float;
using f32x16 = __attribute__((ext_vector_type(16))) float;
using uint2v = __attribute__((ext_vector_type(2))) u32;

#define T_SEQ 2048
#define C_DIM 1024
#define NH 16
#define HD 64

#if __has_builtin(__builtin_amdgcn_exp2f)
#define EXP2(x) __builtin_amdgcn_exp2f(x)
#else
#define EXP2(x) exp2f(x)
#endif

__device__ __forceinline__ u16 f2bf(float f) {
    unsigned int u = __float_as_uint(f);
    unsigned int r = (u + 0x7fffu + ((u >> 16) & 1u)) >> 16;
    return (u16)r;
}
__device__ __forceinline__ u32 cvtpk(float lo, float hi) {
    u32 r;
    asm("v_cvt_pk_bf16_f32 %0, %1, %2" : "=v"(r) : "v"(lo), "v"(hi));
    return r;
}
__device__ __forceinline__ short8 mk8(u32 a, u32 b, u32 c, u32 d) {
    union { u32 u[4]; short8 s; } t;
    t.u[0] = a; t.u[1] = b; t.u[2] = c; t.u[3] = d;
    return t.s;
}
// global -> LDS direct DMA, 16B per lane; LDS dest = wave-uniform base + lane*16
__device__ __forceinline__ void gl_lds16(const u16* g, u16* l) {
    __builtin_amdgcn_global_load_lds(
        (const __attribute__((address_space(1))) unsigned int*)g,
        (__attribute__((address_space(3))) unsigned int*)l, 16, 0, 0);
}
template <int N> __device__ __forceinline__ void s_vmcnt();
template <> __device__ __forceinline__ void s_vmcnt<0>() {
    asm volatile("s_waitcnt vmcnt(0)" ::: "memory");
}
template <> __device__ __forceinline__ void s_vmcnt<2>() {
    asm volatile("s_waitcnt vmcnt(2)" ::: "memory");
}
template <> __device__ __forceinline__ void s_vmcnt<4>() {
    asm volatile("s_waitcnt vmcnt(4)" ::: "memory");
}
template <> __device__ __forceinline__ void s_vmcnt<6>() {
    asm volatile("s_waitcnt vmcnt(6)" ::: "memory");
}
template <> __device__ __forceinline__ void s_vmcnt<8>() {
    asm volatile("s_waitcnt vmcnt(8)" ::: "memory");
}
// raw workgroup barrier with compiler memory fences, NO hardware waitcnt drain
__device__ __forceinline__ void BAR() {
    asm volatile("" ::: "memory");
    __builtin_amdgcn_s_barrier();
    asm volatile("" ::: "memory");
}

// ---------------- fp32 -> bf16 convert, 8 elems/thread ----------------
__global__ __launch_bounds__(256) void cvt_f32_bf16(const float* __restrict__ in,
                                                    u16* __restrict__ out, int n8) {
    int i = blockIdx.x * blockDim.x + threadIdx.x;
    if (i >= n8) return;
    const float4* p = (const float4*)in + (size_t)i * 2;
    float4 a = p[0], b = p[1];
    short8 o;
    o[0] = (short)f2bf(a.x); o[1] = (short)f2bf(a.y);
    o[2] = (short)f2bf(a.z); o[3] = (short)f2bf(a.w);
    o[4] = (short)f2bf(b.x); o[5] = (short)f2bf(b.y);
    o[6] = (short)f2bf(b.z); o[7] = (short)f2bf(b.w);
    *(short8*)(out + (size_t)i * 8) = o;
}

// ------------- bf16 GEMM, 8-phase interleaved (T2+T3+T4+T5) -------------
// BM=256, BN=64*NI, BK=64, 512 thr = 8 waves (2M x 4N), per-wave 128 x 16*NI.
// Per K-tile 4 phases: {ds_read subtile || 1 half-tile gl_lds16 prefetch ||
// barrier || 16 MFMA || barrier}. Half-tile issue slots: A0/A1(u+1) @ ph0/1,
// B0/B1(u+2) @ ph2/3 (each half freed one barrier before its slot). Counted
// vmcnt(NI) once per K-tile at ph3 — loads stay in flight across barriers.
// EPI=0: scatter Q (x0.125*log2e), K to [BH][T][D]; V transposed to [BH][D][T].
// EPI=1: fp32 C + bias.
template <int EPI, int NI, int NXT>
__global__ __launch_bounds__(512, 2) void gemm8(const u16* __restrict__ A,
                                                const u16* __restrict__ Bt,
                                                const float* __restrict__ bias,
                                                u16* __restrict__ qb,
                                                u16* __restrict__ kb,
                                                u16* __restrict__ vtb,
                                                float* __restrict__ Cf, int N_) {
    constexpr int KD = 1024, NT = KD / 64, BN = 64 * NI, BI = NI / 2;
    constexpr int NWG = NXT * 32;
    __shared__ __align__(16) u16 LA[2][2][128 * 64];
    __shared__ __align__(16) u16 LB[2][2][(BN / 2) * 64];
    const int tid = threadIdx.x;
    const int lane = tid & 63, wid = tid >> 6;
    const int li = lane & 15, g = lane >> 4;
    const int wm = wid >> 2, wn = wid & 3;
    const int x7 = li & 7;
    const int r8 = lane >> 3, sch = (lane & 7) ^ r8;    // pre-swizzled source chunk

    const int b0 = blockIdx.x;
    const int swz = (b0 & 7) * (NWG >> 3) + (b0 >> 3);  // XCD-chunked
    const int bx = swz % NXT, by = swz / NXT;
    const size_t m0 = (size_t)by * 256, n0 = (size_t)bx * BN;

    auto stageA = [&](int buf, int half, int t) {
        const u16* src = A + (m0 + half * 128 + wid * 16 + r8) * (size_t)KD + t * 64 + sch * 8;
        u16* dst = &LA[buf][half][wid * 16 * 64];
        gl_lds16(src, dst);
        gl_lds16(src + 8 * (size_t)KD, dst + 8 * 64);
    };
    auto stageB = [&](int buf, int half, int t) {
        const u16* src = Bt + (n0 + half * (BN / 2) + wid * 8 * BI + r8) * (size_t)KD + t * 64 + sch * 8;
        u16* dst = &LB[buf][half][wid * 8 * BI * 64];
#pragma unroll
        for (int j = 0; j < BI; ++j)
            gl_lds16(src + (size_t)j * 8 * KD, dst + j * 8 * 64);
    };

    f32x4 acc[8][NI] = {};

    // prologue: tiles 0 and 1 fully staged; wait tile 0 resident (tile 1 in flight)
    stageA(0, 0, 0); stageA(0, 1, 0);
    stageB(0, 0, 0); stageB(0, 1, 0);
    stageA(1, 0, 1); stageA(1, 1, 1);
    stageB(1, 0, 1); stageB(1, 1, 1);
    s_vmcnt<4 + NI>();
    BAR();

#pragma unroll 2
    for (int u = 0; u < NT; ++u) {
        const int b = u & 1;
        short8 bf[NI][2];
#pragma unroll
        for (int p = 0; p < 4; ++p) {
            if (p == 0) {
#pragma unroll
                for (int ni = 0; ni < NI; ++ni)
#pragma unroll
                    for (int kk = 0; kk < 2; ++kk)
                        bf[ni][kk] = *(const short8*)&LB[b][wn >> 1]
                            [((wn & 1) * 16 * NI + ni * 16 + li) * 64 +
                             (((kk * 4 + g) ^ x7) * 8)];
            }
            short8 af[2][2];
#pragma unroll
            for (int m2 = 0; m2 < 2; ++m2)
#pragma unroll
                for (int kk = 0; kk < 2; ++kk)
                    af[m2][kk] = *(const short8*)&LA[b][wm]
                        [(p * 32 + m2 * 16 + li) * 64 + (((kk * 4 + g) ^ x7) * 8)];
            // half-tile prefetch slot (freed exactly one barrier earlier)
            if (p == 0)      { if (u > 0 && u + 1 < NT) stageA(b ^ 1, 0, u + 1); }
            else if (p == 1) { if (u > 0 && u + 1 < NT) stageA(b ^ 1, 1, u + 1); }
            else if (p == 2) { if (u + 2 < NT) stageB(b, 0, u + 2); }
            else             { if (u + 2 < NT) stageB(b, 1, u + 2); }
            BAR();
            __builtin_amdgcn_s_setprio(1);
#pragma unroll
            for (int kk = 0; kk < 2; ++kk)
#pragma unroll
                for (int m2 = 0; m2 < 2; ++m2)
#pragma unroll
                    for (int ni = 0; ni < NI; ++ni)
                        acc[p * 2 + m2][ni] = __builtin_amdgcn_mfma_f32_16x16x32_bf16(
                            af[m2][kk], bf[ni][kk], acc[p * 2 + m2][ni], 0, 0, 0);
            __builtin_amdgcn_s_setprio(0);
            if (p == 3) {
                if (u < NT - 2) s_vmcnt<NI>();          // next tile resident; 2 B-halves in flight
                else if (u == NT - 2) s_vmcnt<0>();     // final tile: drain
            }
            BAR();
        }
    }

#pragma unroll
    for (int mi = 0; mi < 8; mi++)
#pragma unroll
        for (int ni = 0; ni < NI; ni++)
#pragma unroll
            for (int r = 0; r < 4; r++) {
                size_t row = m0 + wm * 128 + mi * 16 + g * 4 + r;
                size_t col = n0 + wn * 16 * NI + ni * 16 + li;
                float val = acc[mi][ni][r] + bias[col];
                if (EPI == 0) {
                    int which = (int)(col >> 10);
                    int rem = (int)(col & 1023);
                    int h = rem >> 6, d = rem & 63;
                    size_t b = row >> 11, t = row & 2047;
                    if (which == 0) {
                        val *= 0.18033688f;     // (1/8)*log2(e): exp2-domain softmax
                        qb[(((b * NH) + h) * T_SEQ + t) * HD + d] = f2bf(val);
                    } else if (which == 1) {
                        kb[(((b * NH) + h) * T_SEQ + t) * HD + d] = f2bf(val);
                    } else {                    // V: write transposed [BH][D][T]
                        vtb[(((b * NH) + h) * HD + d) * T_SEQ + t] = f2bf(val);
                    }
                } else {
                    Cf[row * (size_t)N_ + col] = val;
                }
            }
}

// ---------------- causal flash attention, swapped-QK 32x32 MFMA ----------------
// 512 blocks, each handles the q-tile PAIR (15-p, p) sequentially -> exactly
// 34 KV-tile-units per block (dispatch-order-immune balance). 256 thr = 4 waves
// x 32 q-rows. K/Vt staged via global_load_lds, XOR-swizzled source, dbuf.
__global__ __launch_bounds__(256) void attn_fwd2(const u16* __restrict__ Q,
                                                 const u16* __restrict__ K,
                                                 const u16* __restrict__ Vt,
                                                 u16* __restrict__ O) {
    __shared__ __align__(16) u16 KL[2][64 * 64];
    __shared__ __align__(16) u16 VL[2][64 * 64];
    const int tid = threadIdx.x;
    const int lane = tid & 63, wid = tid >> 6;
    const int l31 = lane & 31, hi = lane >> 5;

    const int wg = blockIdx.x;
    const int xcd = wg & 7, idx = wg >> 3;       // idx 0..63
    const int bh = (xcd << 3) | (idx >> 3);      // 8 bh per XCD -> K/V L2-resident
    const int pair = idx & 7;
    const size_t bhT = (size_t)bh * T_SEQ;
    const int srow8 = lane >> 3, sch = lane & 7;
    const int b = bh >> 4, h = bh & 15;
    const int x7 = l31 & 7;

    for (int seg = 0; seg < 2; ++seg) {
        const int qt = seg ? pair : (15 - pair);
        const int q0 = qt * 128;
        const int qw0 = q0 + wid * 32;
        const int nkt = 2 * qt + 2;

        short8 qf[4];
        {
            const u16* qp = Q + (bhT + qw0 + l31) * HD + hi * 8;
#pragma unroll
            for (int s = 0; s < 4; s++) qf[s] = *(const short8*)(qp + s * 16);
        }

        f32x16 o0 = {}, o1 = {};
        float m_run = -3e38f, l_run = 0.f;

        // prologue: stage tile 0 into buffer 0
#pragma unroll
        for (int i = 0; i < 2; i++) {
            int row = wid * 16 + i * 8 + srow8;
            int ch = sch ^ (row & 7);
            gl_lds16(K + (bhT + row) * HD + ch * 8, &KL[0][(wid * 16 + i * 8) * 64]);
            gl_lds16(Vt + ((size_t)bh * HD + row) * T_SEQ + ch * 8,
                     &VL[0][(wid * 16 + i * 8) * 64]);
        }

        for (int kt = 0; kt < nkt; kt++) {
            __syncthreads();   // drains vmcnt: tile kt resident; prev compute done
            if (kt + 1 < nkt) {
                const int kv0n = (kt + 1) * 64;
                const int nb = (kt + 1) & 1;
#pragma unroll
                for (int i = 0; i < 2; i++) {
                    int row = wid * 16 + i * 8 + srow8;
                    int ch = sch ^ (row & 7);
                    gl_lds16(K + (bhT + kv0n + row) * HD + ch * 8,
                             &KL[nb][(wid * 16 + i * 8) * 64]);
                    gl_lds16(Vt + ((size_t)bh * HD + row) * T_SEQ + kv0n + ch * 8,
                             &VL[nb][(wid * 16 + i * 8) * 64]);
                }
            }
            const int kv0 = kt * 64;
            if (kv0 > qw0) continue;     // wave-uniform; barriers stay at loop top
            const u16* KLb = KL[kt & 1];
            const u16* VLb = VL[kt & 1];

            // S^T[kv][q] = K . Q^T  (two kv-halves of 32); Q carries 0.125*log2e
            f32x16 s0 = {}, s1 = {};
            __builtin_amdgcn_s_setprio(1);
#pragma unroll
            for (int sl = 0; sl < 4; sl++) {
                int ch = ((sl * 2 + hi) ^ x7) * 8;
                short8 ka = *(const short8*)&KLb[l31 * 64 + ch];
                s0 = __builtin_amdgcn_mfma_f32_32x32x16_bf16(ka, qf[sl], s0, 0, 0, 0);
                short8 kb2 = *(const short8*)&KLb[(32 + l31) * 64 + ch];
                s1 = __builtin_amdgcn_mfma_f32_32x32x16_bf16(kb2, qf[sl], s1, 0, 0, 0);
            }
            __builtin_amdgcn_s_setprio(0);

            const int qg = qw0 + l31;
            if (kv0 + 63 > qw0) {       // boundary tile: causal mask
#pragma unroll
                for (int r = 0; r < 16; r++) {
                    int kvr = kv0 + (r & 3) + 8 * (r >> 2) + 4 * hi;
                    if (kvr > qg) s0[r] = -1e30f;
                    if (kvr + 32 > qg) s1[r] = -1e30f;
                }
            }

            // per-q max (lane-local) + partner exchange
            float pm = -3e38f;
#pragma unroll
            for (int r = 0; r < 16; r++) pm = fmaxf(fmaxf(s0[r], s1[r]), pm);
            pm = fmaxf(pm, __shfl_xor(pm, 32));

            // defer-max (log2 domain): rescale only if some q grew by > 8 bits
            if (!__all(pm <= m_run + 8.0f)) {
                float mnew = fmaxf(m_run, pm);
                float alpha = EXP2(m_run - mnew);
                l_run *= alpha;
                m_run = mnew;
#pragma unroll
                for (int r = 0; r < 16; r++) {
                    int qr = (r & 3) + 8 * (r >> 2) + 4 * hi;
                    float ar = __shfl(alpha, qr);
                    o0[r] *= ar;
                    o1[r] *= ar;
                }
            }

            // P = 2^(S - m), row-sum into l
            float ls = 0.f;
#pragma unroll
            for (int r = 0; r < 16; r++) {
                float p0 = EXP2(s0[r] - m_run);
                float p1 = EXP2(s1[r] - m_run);
                s0[r] = p0; s1[r] = p1;
                ls += p0 + p1;
            }
            ls += __shfl_xor(ls, 32);
            l_run += ls;

            // P -> bf16 A-frags via cvt_pk + permlane32_swap; PV kv 0..31
            {
                u32 c0 = cvtpk(s0[0], s0[1]),   c1 = cvtpk(s0[2], s0[3]),
                    c2 = cvtpk(s0[4], s0[5]),   c3 = cvtpk(s0[6], s0[7]),
                    c4 = cvtpk(s0[8], s0[9]),   c5 = cvtpk(s0[10], s0[11]),
                    c6 = cvtpk(s0[12], s0[13]), c7 = cvtpk(s0[14], s0[15]);
                uint2v wA = __builtin_amdgcn_permlane32_swap(c0, c2, false, false);
                uint2v wB = __builtin_amdgcn_permlane32_swap(c1, c3, false, false);
                uint2v wC = __builtin_amdgcn_permlane32_swap(c4, c6, false, false);
                uint2v wD = __builtin_amdgcn_permlane32_swap(c5, c7, false, false);
                short8 paA = mk8(wA[0], wB[0], wA[1], wB[1]);
                short8 paB = mk8(wC[0], wD[0], wC[1], wD[1]);
                __builtin_amdgcn_s_setprio(1);
#pragma unroll
                for (int sl = 0; sl < 2; sl++) {
                    short8 pa = (sl == 0) ? paA : paB;
                    int ch = ((sl * 2 + hi) ^ x7) * 8;
                    short8 va = *(const short8*)&VLb[l31 * 64 + ch];
                    o0 = __builtin_amdgcn_mfma_f32_32x32x16_bf16(pa, va, o0, 0, 0, 0);
                    short8 vb2 = *(const short8*)&VLb[(32 + l31) * 64 + ch];
                    o1 = __builtin_amdgcn_mfma_f32_32x32x16_bf16(pa, vb2, o1, 0, 0, 0);
                }
                __builtin_amdgcn_s_setprio(0);
            }
            // PV kv 32..63
            {
                u32 c0 = cvtpk(s1[0], s1[1]),   c1 = cvtpk(s1[2], s1[3]),
                    c2 = cvtpk(s1[4], s1[5]),   c3 = cvtpk(s1[6], s1[7]),
                    c4 = cvtpk(s1[8], s1[9]),   c5 = cvtpk(s1[10], s1[11]),
                    c6 = cvtpk(s1[12], s1[13]), c7 = cvtpk(s1[14], s1[15]);
                uint2v wA = __builtin_amdgcn_permlane32_swap(c0, c2, false, false);
                uint2v wB = __builtin_amdgcn_permlane32_swap(c1, c3, false, false);
                uint2v wC = __builtin_amdgcn_permlane32_swap(c4, c6, false, false);
                uint2v wD = __builtin_amdgcn_permlane32_swap(c5, c7, false, false);
                short8 paC = mk8(wA[0], wB[0], wA[1], wB[1]);
                short8 paD = mk8(wC[0], wD[0], wC[1], wD[1]);
                __builtin_amdgcn_s_setprio(1);
#pragma unroll
                for (int sl = 2; sl < 4; sl++) {
                    short8 pa = (sl == 2) ? paC : paD;
                    int ch = ((sl * 2 + hi) ^ x7) * 8;
                    short8 va = *(const short8*)&VLb[l31 * 64 + ch];
                    o0 = __builtin_amdgcn_mfma_f32_32x32x16_bf16(pa, va, o0, 0, 0, 0);
                    short8 vb2 = *(const short8*)&VLb[(32 + l31) * 64 + ch];
                    o1 = __builtin_amdgcn_mfma_f32_32x32x16_bf16(pa, vb2, o1, 0, 0, 0);
                }
                __builtin_amdgcn_s_setprio(0);
            }
        }

        // epilogue: O / l, write bf16 to [B][T][C]
        const float inv = 1.0f / l_run;       // lane's own q-row = l31
#pragma unroll
        for (int r = 0; r < 16; r++) {
            int qr = (r & 3) + 8 * (r >> 2) + 4 * hi;
            float invr = __shfl(inv, qr);
            int t = q0 + wid * 32 + qr;
            size_t rowoff = ((size_t)b * T_SEQ + t) * C_DIM + h * HD;
            O[rowoff + l31]      = f2bf(o0[r] * invr);
            O[rowoff + 32 + l31] = f2bf(o1[r] * invr);
        }
    }
}

extern "C" void kernel_launch(void* const* d_in, const int* in_sizes, int n_in,
                              void* d_out, int out_size, void* d_ws, size_t ws_size,
                              hipStream_t stream) {
    const float* x     = (const float*)d_in[0];
    // d_in[1] = mask (causal, analytic — unused)
    const float* W_qkv = (const float*)d_in[2];
    const float* b_qkv = (const float*)d_in[3];
    const float* W_out = (const float*)d_in[4];
    const float* b_out = (const float*)d_in[5];
    float* out = (float*)d_out;

    char* w = (char*)d_ws;
    u16* xb    = (u16*)(w);                 // 16 MB: x-bf16; dead after QKV -> attn out
    u16* wqkvb = (u16*)(w + 16777216);
    u16* woutb = (u16*)(w + 23068672);
    u16* qb    = (u16*)(w + 25165824);
    u16* kb    = (u16*)(w + 41943040);
    u16* vtb   = (u16*)(w + 58720256);      // V^T [BH][D][T], written by QKV GEMM
    u16* attnb = xb;

    cvt_f32_bf16<<<4096, 256, 0, stream>>>(x, xb, 1048576);
    cvt_f32_bf16<<<1536, 256, 0, stream>>>(W_qkv, wqkvb, 393216);
    cvt_f32_bf16<<<512, 256, 0, stream>>>(W_out, woutb, 131072);

    // QKV: [8192x1024] x [3072x1024]^T; 256x256 tiles -> 32x12 = 384 blocks
    gemm8<0, 4, 12><<<384, 512, 0, stream>>>(xb, wqkvb, b_qkv, qb, kb, vtb,
                                             nullptr, 3072);

    attn_fwd2<<<512, 256, 0, stream>>>(qb, kb, vtb, attnb);

    // out-proj: [8192x1024] x [1024x1024]^T; 256x128 tiles -> 32x8 = 256 blocks
    gemm8<1, 2, 8><<<256, 512, 0, stream>>>(attnb, woutb, b_out, nullptr, nullptr,
                                            nullptr, out, 1024);
}